// Round 9
// baseline (321.241 us; speedup 1.0000x reference)
//
#include <hip/hip_runtime.h>
#include <hip/hip_bf16.h>

typedef short  short8  __attribute__((ext_vector_type(8)));
typedef float  float4v __attribute__((ext_vector_type(4)));
typedef int    int4v   __attribute__((ext_vector_type(4)));

#define SEQ    4096
#define DHEAD  64
#define NBLK   64
#define NCHUNK 8         // split factor for full rows (qb 0, 63)
#define CHK    8         // key blocks per split chunk
#define WGPB   78        // units per (b,h): 62 regular + 2*8 split
#define ENTRY_FLOATS 4160   // per split-partial: 64 l + 64*64 o
#define KS_ELEMS (2L * 16 * 4096 * 64)   // bf16 K copy elems (= 16 MB)
#define QSCALE 0.125f    // 1/sqrt(64)

__device__ __forceinline__ short f2bf(float f) {
    unsigned u = __float_as_uint(f);
    u += 0x7fffu + ((u >> 16) & 1u);   // RNE to bf16
    return (short)(u >> 16);
}

__device__ __forceinline__ unsigned cvt_pk_bf16(float lo, float hi) {
    unsigned r;
    asm("v_cvt_pk_bf16_f32 %0, %1, %2" : "=v"(r) : "v"(lo), "v"(hi));
    return r;
}

__device__ __forceinline__ void gload16(const void* g, void* l) {
    __builtin_amdgcn_global_load_lds(
        (const __attribute__((address_space(1))) unsigned int*)g,
        (__attribute__((address_space(3))) unsigned int*)l, 16, 0, 0);
}

// ---------------- prep: fp32 -> bf16, XCD-aligned ---------------------------------------
// K: swizzled 64x128B LDS image (staged via gload_lds, read with XOR in main).
// V^T: LINEAR 64x128B blocks (read per-lane directly in main; no swizzle needed).
__global__ __launch_bounds__(256)
void bigbird_prep(const float* __restrict__ K,
                  const float* __restrict__ V,
                  short* __restrict__ wsS) {
    __shared__ float tile[64 * 65];
    const int gi   = blockIdx.x;
    const int xcd  = gi & 7;
    const int slot = gi >> 3;              // 0..255
    const int bh   = xcd + 8 * (slot >> 6);
    const int kb   = slot & 63;
    const int t  = threadIdx.x;
    char* Ks = (char*)wsS;
    char* VT = (char*)(wsS + KS_ELEMS);
    const long blk_off = (long)(bh * 64 + kb) * 8192;   // bytes per 64x64 bf16 block

    const int row = t >> 2, seg = t & 3;
    const long gsrc = ((long)bh * SEQ + kb * 64 + row) * DHEAD + seg * 16;

    // K: convert, store at swizzled 16B slots
    {
        const float* kp = K + gsrc;
        short8 s0, s1;
#pragma unroll
        for (int i = 0; i < 4; ++i) {
            float4v x = ((const float4v*)kp)[i];
#pragma unroll
            for (int jj = 0; jj < 4; ++jj) {
                short v = f2bf(x[jj]);
                if (i < 2) s0[i * 4 + jj] = v; else s1[(i - 2) * 4 + jj] = v;
            }
        }
        char* kbase = Ks + blk_off + (long)row * 128;
        const int sw = (row & 7) << 4;
        *(short8*)(kbase + ((seg * 32)      ^ sw)) = s0;
        *(short8*)(kbase + ((seg * 32 + 16) ^ sw)) = s1;
    }
    // V: through LDS transpose, store V^T rows (d-major) LINEAR
    {
        const float* vp = V + gsrc;
#pragma unroll
        for (int i = 0; i < 4; ++i) {
            float4v x = ((const float4v*)vp)[i];
#pragma unroll
            for (int jj = 0; jj < 4; ++jj)
                tile[row * 65 + seg * 16 + i * 4 + jj] = x[jj];
        }
    }
    __syncthreads();
    {
        const int d = t >> 2, kk = t & 3;
        short8 s0, s1;
#pragma unroll
        for (int i = 0; i < 8; ++i) {
            s0[i] = f2bf(tile[(kk * 16 + i) * 65 + d]);
            s1[i] = f2bf(tile[(kk * 16 + 8 + i) * 65 + d]);
        }
        char* vbase = VT + blk_off + (long)d * 128;
        *(short8*)(vbase + kk * 32)      = s0;
        *(short8*)(vbase + kk * 32 + 16) = s1;
    }
}

// ---------------- main: R4 skeleton; K staged in LDS (24KB), V per-lane direct ----------
// 4 blocks/CU (16 waves). Distance-2 counted-vmcnt pipeline for K staging; V fragments
// loaded per-lane from L2-resident linear V^T at iteration top (covered by QK/exp/pack
// latency + TLP). V loads issued BEFORE stage(it+2), so end-of-iter vmcnt(2) still
// guarantees stage(it+1) landed while stage(it+2) stays in flight.
__global__ __launch_bounds__(256, 4)
void bigbird_main(const float* __restrict__ Q,
                  const int* __restrict__ rand_attn,
                  float* __restrict__ out,
                  const short* __restrict__ wsS,
                  float* __restrict__ part) {
    __shared__ short kb_s[3][4096];   // 8KB swizzled K block x3 (24 KB total)

    const int gi   = blockIdx.x;
    const int xcd  = gi & 7;
    const int slot = gi >> 3;               // 0..311
    const int bh   = xcd + 8 * (slot / WGPB);
    const int j    = slot % WGPB;
    const bool split = (j >= 62);
    int qb, chunk = 0, nk;
    if (!split) { qb = j + 1; nk = (qb == 1 || qb == 62) ? 7 : 8; }
    else        { int s2 = j - 62; qb = (s2 >> 3) ? 63 : 0; chunk = s2 & 7; nk = CHK; }

    const int tid  = threadIdx.x;
    const int wave = tid >> 6;
    const int lane = tid & 63;
    const int l15  = lane & 15;
    const int quad = lane >> 4;

    const long base = (long)bh * SEQ * DHEAD;
    const char* Ksb = (const char*)wsS + (long)bh * (NBLK * 8192);
    const char* VTb = (const char*)(wsS + KS_ELEMS) + (long)bh * (NBLK * 8192);

    int rnd0 = 0, rnd1 = 0, rnd2 = 0;
    if (!split) {
        const int rbase = (bh * 62 + (qb - 1)) * 3;
        rnd0 = rand_attn[rbase + 0];
        rnd1 = rand_attn[rbase + 1];
        rnd2 = rand_attn[rbase + 2];
    }
    auto kb_of = [&](int it) -> int {
        if (split) return chunk * CHK + it;
        const int nband = (qb == 1 || qb == 62) ? 4 : 5;
        if (it >= nband) {
            const int ir = it - nband;
            return ir == 0 ? rnd0 : ir == 1 ? rnd1 : rnd2;
        }
        if (qb == 1)  return it <= 2 ? it : 63;          // 0,1,2,63
        if (qb == 62) return it == 0 ? 0 : 60 + it;      // 0,61,62,63
        return it == 0 ? 0 : it <= 3 ? qb - 2 + it : 63; // 0,qb-1,qb,qb+1,63
    };

    // Q fragments from fp32, pre-scaled by 1/8 (= 1/sqrt(64), exact)
    short8 aq0, aq1;
    {
        const float* qp = Q + base + (long)(qb * 64 + wave * 16 + l15) * DHEAD + quad * 8;
        float4v x0 = *(const float4v*)(qp);
        float4v x1 = *(const float4v*)(qp + 4);
        float4v x2 = *(const float4v*)(qp + 32);
        float4v x3 = *(const float4v*)(qp + 36);
#pragma unroll
        for (int i = 0; i < 4; ++i) {
            aq0[i]     = f2bf(QSCALE * x0[i]);
            aq0[4 + i] = f2bf(QSCALE * x1[i]);
            aq1[i]     = f2bf(QSCALE * x2[i]);
            aq1[4 + i] = f2bf(QSCALE * x3[i]);
        }
    }

    // K staging only: exactly 2 gload16 (2 vmcnt events) per thread per stage (8KB)
    auto stage = [&](int kb, int buf) {
        const char* kg = Ksb + (long)kb * 8192;
        char* kd = (char*)kb_s[buf];
        const int off = tid * 16;
        gload16(kg + off,        kd + off);
        gload16(kg + 4096 + off, kd + 4096 + off);
    };

    float4v o[4];
#pragma unroll
    for (int nt = 0; nt < 4; ++nt) o[nt] = (float4v)0.0f;
    float l_acc = 0.0f;   // per-lane partial denominator for q = wave*16+l15

    // drain Q/rand loads so vmcnt counts ONLY staging loads from here on
    asm volatile("s_waitcnt vmcnt(0) lgkmcnt(0)" ::: "memory");

    stage(kb_of(0), 0);                 // nk >= 7 always
    stage(kb_of(1), 1);
    asm volatile("s_waitcnt vmcnt(2)" ::: "memory");   // buf0 landed; buf1 in flight
    __builtin_amdgcn_s_barrier();

    for (int it = 0; it < nk; ++it) {
        const int cur = it % 3;
        const int kb_c = kb_of(it);
        const bool issue = (it + 2 < nk);   // uniform per block

        // V fragments for THIS iteration: per-lane 16B loads from linear V^T (L2-local).
        // Issued BEFORE stage(it+2) so vmcnt ordering keeps stage loads newest.
        short8 vf[4][2];
        {
            const char* vBp = VTb + (long)kb_c * 8192;
#pragma unroll
            for (int nt = 0; nt < 4; ++nt) {
                const char* vr = vBp + (nt * 16 + l15) * 128 + quad * 16;
                vf[nt][0] = *(const short8*)(vr);
                vf[nt][1] = *(const short8*)(vr + 64);
            }
        }
        if (issue) stage(kb_of(it + 2), (it + 2) % 3);

        __builtin_amdgcn_s_setprio(1);
        // ---- S^T = K * Q^T : p[nt] rows k = nt*16+quad*4+r, col q = l15 ----
        float4v p[4];
#pragma unroll
        for (int nt = 0; nt < 4; ++nt) {
            const int rr = nt * 16 + l15;
            const char* kro = (const char*)kb_s[cur] + rr * 128;
            const int sw = (rr & 7) << 4;
            short8 b0 = *(const short8*)(kro + ((quad * 16)      ^ sw));
            short8 b1 = *(const short8*)(kro + ((64 + quad * 16) ^ sw));
            float4v acc = (float4v)0.0f;
            acc = __builtin_amdgcn_mfma_f32_16x16x32_bf16(b0, aq0, acc, 0, 0, 0);
            acc = __builtin_amdgcn_mfma_f32_16x16x32_bf16(b1, aq1, acc, 0, 0, 0);
            p[nt] = acc;
        }

        // ---- fixed-max softmax: P = exp(S); per-lane partial l ----
#pragma unroll
        for (int nt = 0; nt < 4; ++nt) {
#pragma unroll
            for (int r = 0; r < 4; ++r) p[nt][r] = __expf(p[nt][r]);
        }
        l_acc += ((p[0][0] + p[0][1]) + (p[0][2] + p[0][3]))
               + ((p[1][0] + p[1][1]) + (p[1][2] + p[1][3]))
               + ((p[2][0] + p[2][1]) + (p[2][2] + p[2][3]))
               + ((p[3][0] + p[3][1]) + (p[3][2] + p[3][3]));

        // ---- O^T += V^T * P^T ; V fragments already in registers ----
#pragma unroll
        for (int f = 0; f < 2; ++f) {
            unsigned x0 = cvt_pk_bf16(p[2 * f][0],     p[2 * f][1]);
            unsigned x1 = cvt_pk_bf16(p[2 * f][2],     p[2 * f][3]);
            unsigned y0 = cvt_pk_bf16(p[2 * f + 1][0], p[2 * f + 1][1]);
            unsigned y1 = cvt_pk_bf16(p[2 * f + 1][2], p[2 * f + 1][3]);
            asm("v_permlane32_swap_b32 %0, %1" : "+v"(x0), "+v"(y0));
            asm("v_permlane32_swap_b32 %0, %1" : "+v"(x1), "+v"(y1));
            asm("v_permlane16_swap_b32 %0, %1" : "+v"(x0), "+v"(y0));
            asm("v_permlane16_swap_b32 %0, %1" : "+v"(x1), "+v"(y1));
            int4v wi; wi[0] = (int)x0; wi[1] = (int)x1; wi[2] = (int)y0; wi[3] = (int)y1;
            union { int4v i; short8 s; } pu; pu.i = wi;
            const short8 pf = pu.s;   // element i = P^T[k = f*32 + quad*8 + i][q = l15]
#pragma unroll
            for (int nt = 0; nt < 4; ++nt)
                o[nt] = __builtin_amdgcn_mfma_f32_16x16x32_bf16(vf[nt][f], pf, o[nt], 0, 0, 0);
        }
        __builtin_amdgcn_s_setprio(0);

        // counted drain: require tile it+1's 2 K-loads done; it+2's 2 may stay in flight
        if (issue) asm volatile("s_waitcnt vmcnt(2)" ::: "memory");
        else       asm volatile("s_waitcnt vmcnt(0)" ::: "memory");
        __builtin_amdgcn_s_barrier();
    }

    // full denominator: sum the 4 quads holding this q's k-partials
    l_acc += __shfl_xor(l_acc, 16, 64);
    l_acc += __shfl_xor(l_acc, 32, 64);

    if (!split) {
        const float inv = 1.0f / l_acc;
        float* op = out + base + (long)(qb * 64 + wave * 16 + l15) * DHEAD;
#pragma unroll
        for (int nt = 0; nt < 4; ++nt) {
            float4v vv;
#pragma unroll
            for (int r = 0; r < 4; ++r) vv[r] = o[nt][r] * inv;
            *(float4v*)(op + nt * 16 + quad * 4) = vv;   // row q, cols nt*16+quad*4..+3
        }
    } else {
        float* wsp = part + (long)((bh * 2 + (qb == 63)) * NCHUNK + chunk) * ENTRY_FLOATS;
        if (quad == 0) wsp[wave * 16 + l15] = l_acc;
        float* orow = wsp + 64 + (long)(wave * 16 + l15) * 64;
#pragma unroll
        for (int nt = 0; nt < 4; ++nt) {
            float4v vv;
#pragma unroll
            for (int r = 0; r < 4; ++r) vv[r] = o[nt][r];
            *(float4v*)(orow + nt * 16 + quad * 4) = vv;
        }
    }
}

// ---------------- combine for split rows (plain sums; fixed-max softmax) ----------------
__global__ __launch_bounds__(256)
void bigbird_combine(const float* __restrict__ part, float* __restrict__ out) {
    const int gid = blockIdx.x * 256 + threadIdx.x;   // 262144 total
    const int dim = gid & 63;
    const int row = (gid >> 6) & 63;
    const int sel = (gid >> 12) & 1;
    const int bh  = gid >> 13;

    float num = 0.0f, den = 0.0f;
#pragma unroll
    for (int c = 0; c < NCHUNK; ++c) {
        const float* e = part + (long)((bh * 2 + sel) * NCHUNK + c) * ENTRY_FLOATS;
        den += e[row];
        num += e[64 + row * 64 + dim];
    }
    const int qb = sel ? 63 : 0;
    out[((long)bh * SEQ + qb * 64 + row) * DHEAD + dim] = num / den;
}

extern "C" void kernel_launch(void* const* d_in, const int* in_sizes, int n_in,
                              void* d_out, int out_size, void* d_ws, size_t ws_size,
                              hipStream_t stream) {
    const float* Q       = (const float*)d_in[0];
    const float* K       = (const float*)d_in[1];
    const float* V       = (const float*)d_in[2];
    const int* rand_attn = (const int*)d_in[3];
    float* out           = (float*)d_out;
    short* wsS           = (short*)d_ws;
    float* part          = (float*)((char*)d_ws + 2L * KS_ELEMS * sizeof(short));

    const int B = 2, H = 16;
    bigbird_prep<<<dim3(B * H * NBLK), dim3(256), 0, stream>>>(K, V, wsS);
    bigbird_main<<<dim3(B * H * WGPB), dim3(256), 0, stream>>>(Q, rand_attn, out, wsS, part);
    bigbird_combine<<<dim3((B * H * 2 * 64 * 64) / 256), dim3(256), 0, stream>>>(part, out);
}

// Round 10
// 274.437 us; speedup vs baseline: 1.1705x; 1.1705x over previous
//
#include <hip/hip_runtime.h>
#include <hip/hip_bf16.h>

typedef short  short8  __attribute__((ext_vector_type(8)));
typedef float  float4v __attribute__((ext_vector_type(4)));
typedef int    int4v   __attribute__((ext_vector_type(4)));

#define SEQ    4096
#define DHEAD  64
#define NBLK   64
#define NCHUNK 8         // split factor for full rows (qb 0, 63)
#define CHK    8         // key blocks per split chunk
#define WGPB   78        // units per (b,h): 62 regular + 2*8 split
#define ENTRY_FLOATS 4160   // per split-partial: 64 l + 64*64 o
#define KS_ELEMS (2L * 16 * 4096 * 64)   // bf16 K copy elems (= 16 MB)
#define QSCALE 0.125f    // 1/sqrt(64)

__device__ __forceinline__ short f2bf(float f) {
    unsigned u = __float_as_uint(f);
    u += 0x7fffu + ((u >> 16) & 1u);   // RNE to bf16
    return (short)(u >> 16);
}

__device__ __forceinline__ unsigned cvt_pk_bf16(float lo, float hi) {
    unsigned r;
    asm("v_cvt_pk_bf16_f32 %0, %1, %2" : "=v"(r) : "v"(lo), "v"(hi));
    return r;
}

__device__ __forceinline__ void gload16(const void* g, void* l) {
    __builtin_amdgcn_global_load_lds(
        (const __attribute__((address_space(1))) unsigned int*)g,
        (__attribute__((address_space(3))) unsigned int*)l, 16, 0, 0);
}

// ---------------- prep: fp32 -> bf16, swizzled 64x128B LDS image, XCD-aligned -----------
// bh = xcd + 8*(slot>>6) matches main's mapping, so ws[bh] lands in the L2 main reads.
__global__ __launch_bounds__(256)
void bigbird_prep(const float* __restrict__ K,
                  const float* __restrict__ V,
                  short* __restrict__ wsS) {
    __shared__ float tile[64 * 65];
    const int gi   = blockIdx.x;
    const int xcd  = gi & 7;
    const int slot = gi >> 3;              // 0..255
    const int bh   = xcd + 8 * (slot >> 6);
    const int kb   = slot & 63;
    const int t  = threadIdx.x;
    char* Ks = (char*)wsS;
    char* VT = (char*)(wsS + KS_ELEMS);
    const long blk_off = (long)(bh * 64 + kb) * 8192;   // bytes per 64x64 bf16 block

    const int row = t >> 2, seg = t & 3;
    const long gsrc = ((long)bh * SEQ + kb * 64 + row) * DHEAD + seg * 16;

    // K: convert, store at swizzled 16B slots
    {
        const float* kp = K + gsrc;
        short8 s0, s1;
#pragma unroll
        for (int i = 0; i < 4; ++i) {
            float4v x = ((const float4v*)kp)[i];
#pragma unroll
            for (int jj = 0; jj < 4; ++jj) {
                short v = f2bf(x[jj]);
                if (i < 2) s0[i * 4 + jj] = v; else s1[(i - 2) * 4 + jj] = v;
            }
        }
        char* kbase = Ks + blk_off + (long)row * 128;
        const int sw = (row & 7) << 4;
        *(short8*)(kbase + ((seg * 32)      ^ sw)) = s0;
        *(short8*)(kbase + ((seg * 32 + 16) ^ sw)) = s1;
    }
    // V: through LDS transpose, then swizzled store of V^T rows (d-major)
    {
        const float* vp = V + gsrc;
#pragma unroll
        for (int i = 0; i < 4; ++i) {
            float4v x = ((const float4v*)vp)[i];
#pragma unroll
            for (int jj = 0; jj < 4; ++jj)
                tile[row * 65 + seg * 16 + i * 4 + jj] = x[jj];
        }
    }
    __syncthreads();
    {
        const int d = t >> 2, kk = t & 3;
        short8 s0, s1;
#pragma unroll
        for (int i = 0; i < 8; ++i) {
            s0[i] = f2bf(tile[(kk * 16 + i) * 65 + d]);
            s1[i] = f2bf(tile[(kk * 16 + 8 + i) * 65 + d]);
        }
        char* vbase = VT + blk_off + (long)d * 128;
        const int sw = (d & 7) << 4;
        *(short8*)(vbase + ((kk * 32)      ^ sw)) = s0;
        *(short8*)(vbase + ((kk * 32 + 16) ^ sw)) = s1;
    }
}

// ---------------- main: R4 pipeline, K triple-buffered (dist-2) + V double-buffered -----
// LDS = 3x8 (K) + 2x8 (V) = 40KB -> exactly 4 blocks/CU (160KB), 16 waves/CU.
// Issue order per iter: V(it+1) then K(it+2); end-of-iter vmcnt(2) drains K(it+1)+V(it+1)
// and leaves K(it+2) in flight. V needs only distance-1 (one full iteration of cover).
__global__ __launch_bounds__(256, 4)
void bigbird_main(const float* __restrict__ Q,
                  const int* __restrict__ rand_attn,
                  float* __restrict__ out,
                  const short* __restrict__ wsS,
                  float* __restrict__ part) {
    __shared__ short kb_s[3][4096];   // 8KB swizzled K block x3
    __shared__ short vt_s[2][4096];   // 8KB swizzled V^T block x2

    const int gi   = blockIdx.x;
    const int xcd  = gi & 7;
    const int slot = gi >> 3;               // 0..311
    const int bh   = xcd + 8 * (slot / WGPB);
    const int j    = slot % WGPB;
    const bool split = (j >= 62);
    int qb, chunk = 0, nk;
    if (!split) { qb = j + 1; nk = (qb == 1 || qb == 62) ? 7 : 8; }
    else        { int s2 = j - 62; qb = (s2 >> 3) ? 63 : 0; chunk = s2 & 7; nk = CHK; }

    const int tid  = threadIdx.x;
    const int wave = tid >> 6;
    const int lane = tid & 63;
    const int l15  = lane & 15;
    const int quad = lane >> 4;

    const long base = (long)bh * SEQ * DHEAD;
    const char* Ksb = (const char*)wsS + (long)bh * (NBLK * 8192);
    const char* VTb = (const char*)(wsS + KS_ELEMS) + (long)bh * (NBLK * 8192);

    int rnd0 = 0, rnd1 = 0, rnd2 = 0;
    if (!split) {
        const int rbase = (bh * 62 + (qb - 1)) * 3;
        rnd0 = rand_attn[rbase + 0];
        rnd1 = rand_attn[rbase + 1];
        rnd2 = rand_attn[rbase + 2];
    }
    auto kb_of = [&](int it) -> int {
        if (split) return chunk * CHK + it;
        const int nband = (qb == 1 || qb == 62) ? 4 : 5;
        if (it >= nband) {
            const int ir = it - nband;
            return ir == 0 ? rnd0 : ir == 1 ? rnd1 : rnd2;
        }
        if (qb == 1)  return it <= 2 ? it : 63;          // 0,1,2,63
        if (qb == 62) return it == 0 ? 0 : 60 + it;      // 0,61,62,63
        return it == 0 ? 0 : it <= 3 ? qb - 2 + it : 63; // 0,qb-1,qb,qb+1,63
    };

    // Q fragments from fp32, pre-scaled by 1/8 (= 1/sqrt(64), exact)
    short8 aq0, aq1;
    {
        const float* qp = Q + base + (long)(qb * 64 + wave * 16 + l15) * DHEAD + quad * 8;
        float4v x0 = *(const float4v*)(qp);
        float4v x1 = *(const float4v*)(qp + 4);
        float4v x2 = *(const float4v*)(qp + 32);
        float4v x3 = *(const float4v*)(qp + 36);
#pragma unroll
        for (int i = 0; i < 4; ++i) {
            aq0[i]     = f2bf(QSCALE * x0[i]);
            aq0[4 + i] = f2bf(QSCALE * x1[i]);
            aq1[i]     = f2bf(QSCALE * x2[i]);
            aq1[4 + i] = f2bf(QSCALE * x3[i]);
        }
    }

    // each stage = exactly 2 gload16 (2 vmcnt events) per thread (8KB per tensor)
    auto stageK = [&](int kb, int buf) {
        const char* kg = Ksb + (long)kb * 8192;
        char* kd = (char*)kb_s[buf];
        const int off = tid * 16;
        gload16(kg + off,        kd + off);
        gload16(kg + 4096 + off, kd + 4096 + off);
    };
    auto stageV = [&](int kb, int buf) {
        const char* vg = VTb + (long)kb * 8192;
        char* vd = (char*)vt_s[buf];
        const int off = tid * 16;
        gload16(vg + off,        vd + off);
        gload16(vg + 4096 + off, vd + 4096 + off);
    };

    float4v o[4];
#pragma unroll
    for (int nt = 0; nt < 4; ++nt) o[nt] = (float4v)0.0f;
    float l_acc = 0.0f;   // per-lane partial denominator for q = wave*16+l15

    // drain Q/rand loads so vmcnt counts ONLY staging loads from here on
    asm volatile("s_waitcnt vmcnt(0) lgkmcnt(0)" ::: "memory");

    // prologue: [K0, V0, K1] -> vmcnt(2) leaves K1 in flight, K0+V0 landed
    stageK(kb_of(0), 0);
    stageV(kb_of(0), 0);
    stageK(kb_of(1), 1);
    asm volatile("s_waitcnt vmcnt(2)" ::: "memory");
    __builtin_amdgcn_s_barrier();

    for (int it = 0; it < nk; ++it) {
        const int kcur = it % 3;
        const int vcur = it & 1;
        const bool haveK2 = (it + 2 < nk);   // uniform per block
        const bool haveV1 = (it + 1 < nk);

        if (haveV1) stageV(kb_of(it + 1), (it + 1) & 1);
        if (haveK2) stageK(kb_of(it + 2), (it + 2) % 3);

        __builtin_amdgcn_s_setprio(1);
        // ---- S^T = K * Q^T : p[nt] rows k = nt*16+quad*4+r, col q = l15 ----
        float4v p[4];
#pragma unroll
        for (int nt = 0; nt < 4; ++nt) {
            const int rr = nt * 16 + l15;
            const char* kro = (const char*)kb_s[kcur] + rr * 128;
            const int sw = (rr & 7) << 4;
            short8 b0 = *(const short8*)(kro + ((quad * 16)      ^ sw));
            short8 b1 = *(const short8*)(kro + ((64 + quad * 16) ^ sw));
            float4v acc = (float4v)0.0f;
            acc = __builtin_amdgcn_mfma_f32_16x16x32_bf16(b0, aq0, acc, 0, 0, 0);
            acc = __builtin_amdgcn_mfma_f32_16x16x32_bf16(b1, aq1, acc, 0, 0, 0);
            p[nt] = acc;
        }

        // ---- fixed-max softmax: P = exp(S); per-lane partial l ----
#pragma unroll
        for (int nt = 0; nt < 4; ++nt) {
#pragma unroll
            for (int r = 0; r < 4; ++r) p[nt][r] = __expf(p[nt][r]);
        }
        l_acc += ((p[0][0] + p[0][1]) + (p[0][2] + p[0][3]))
               + ((p[1][0] + p[1][1]) + (p[1][2] + p[1][3]))
               + ((p[2][0] + p[2][1]) + (p[2][2] + p[2][3]))
               + ((p[3][0] + p[3][1]) + (p[3][2] + p[3][3]));

        // ---- O^T += V^T * P^T ; P^T B-fragment built in-register via permlane swaps ----
#pragma unroll
        for (int f = 0; f < 2; ++f) {
            unsigned x0 = cvt_pk_bf16(p[2 * f][0],     p[2 * f][1]);
            unsigned x1 = cvt_pk_bf16(p[2 * f][2],     p[2 * f][3]);
            unsigned y0 = cvt_pk_bf16(p[2 * f + 1][0], p[2 * f + 1][1]);
            unsigned y1 = cvt_pk_bf16(p[2 * f + 1][2], p[2 * f + 1][3]);
            asm("v_permlane32_swap_b32 %0, %1" : "+v"(x0), "+v"(y0));
            asm("v_permlane32_swap_b32 %0, %1" : "+v"(x1), "+v"(y1));
            asm("v_permlane16_swap_b32 %0, %1" : "+v"(x0), "+v"(y0));
            asm("v_permlane16_swap_b32 %0, %1" : "+v"(x1), "+v"(y1));
            int4v wi; wi[0] = (int)x0; wi[1] = (int)x1; wi[2] = (int)y0; wi[3] = (int)y1;
            union { int4v i; short8 s; } pu; pu.i = wi;
            const short8 pf = pu.s;   // element i = P^T[k = f*32 + quad*8 + i][q = l15]
#pragma unroll
            for (int nt = 0; nt < 4; ++nt) {
                const int rr = nt * 16 + l15;
                const char* vro = (const char*)vt_s[vcur] + rr * 128;
                const int sw = (rr & 7) << 4;
                short8 bv = *(const short8*)(vro + ((f * 64 + quad * 16) ^ sw));
                o[nt] = __builtin_amdgcn_mfma_f32_16x16x32_bf16(bv, pf, o[nt], 0, 0, 0);
            }
        }
        __builtin_amdgcn_s_setprio(0);

        // counted drain: K(it+1)+V(it+1) must land; K(it+2)'s 2 may stay in flight
        if (haveK2) asm volatile("s_waitcnt vmcnt(2)" ::: "memory");
        else        asm volatile("s_waitcnt vmcnt(0)" ::: "memory");
        __builtin_amdgcn_s_barrier();
    }

    // full denominator: sum the 4 quads holding this q's k-partials
    l_acc += __shfl_xor(l_acc, 16, 64);
    l_acc += __shfl_xor(l_acc, 32, 64);

    if (!split) {
        const float inv = 1.0f / l_acc;
        float* op = out + base + (long)(qb * 64 + wave * 16 + l15) * DHEAD;
#pragma unroll
        for (int nt = 0; nt < 4; ++nt) {
            float4v vv;
#pragma unroll
            for (int r = 0; r < 4; ++r) vv[r] = o[nt][r] * inv;
            *(float4v*)(op + nt * 16 + quad * 4) = vv;   // row q, cols nt*16+quad*4..+3
        }
    } else {
        float* wsp = part + (long)((bh * 2 + (qb == 63)) * NCHUNK + chunk) * ENTRY_FLOATS;
        if (quad == 0) wsp[wave * 16 + l15] = l_acc;
        float* orow = wsp + 64 + (long)(wave * 16 + l15) * 64;
#pragma unroll
        for (int nt = 0; nt < 4; ++nt) {
            float4v vv;
#pragma unroll
            for (int r = 0; r < 4; ++r) vv[r] = o[nt][r];
            *(float4v*)(orow + nt * 16 + quad * 4) = vv;
        }
    }
}

// ---------------- combine for split rows (plain sums; fixed-max softmax) ----------------
__global__ __launch_bounds__(256)
void bigbird_combine(const float* __restrict__ part, float* __restrict__ out) {
    const int gid = blockIdx.x * 256 + threadIdx.x;   // 262144 total
    const int dim = gid & 63;
    const int row = (gid >> 6) & 63;
    const int sel = (gid >> 12) & 1;
    const int bh  = gid >> 13;

    float num = 0.0f, den = 0.0f;
#pragma unroll
    for (int c = 0; c < NCHUNK; ++c) {
        const float* e = part + (long)((bh * 2 + sel) * NCHUNK + c) * ENTRY_FLOATS;
        den += e[row];
        num += e[64 + row * 64 + dim];
    }
    const int qb = sel ? 63 : 0;
    out[((long)bh * SEQ + qb * 64 + row) * DHEAD + dim] = num / den;
}

extern "C" void kernel_launch(void* const* d_in, const int* in_sizes, int n_in,
                              void* d_out, int out_size, void* d_ws, size_t ws_size,
                              hipStream_t stream) {
    const float* Q       = (const float*)d_in[0];
    const float* K       = (const float*)d_in[1];
    const float* V       = (const float*)d_in[2];
    const int* rand_attn = (const int*)d_in[3];
    float* out           = (float*)d_out;
    short* wsS           = (short*)d_ws;
    float* part          = (float*)((char*)d_ws + 2L * KS_ELEMS * sizeof(short));

    const int B = 2, H = 16;
    bigbird_prep<<<dim3(B * H * NBLK), dim3(256), 0, stream>>>(K, V, wsS);
    bigbird_main<<<dim3(B * H * WGPB), dim3(256), 0, stream>>>(Q, rand_attn, out, wsS, part);
    bigbird_combine<<<dim3((B * H * 2 * 64 * 64) / 256), dim3(256), 0, stream>>>(part, out);
}

// Round 11
// 259.155 us; speedup vs baseline: 1.2396x; 1.0590x over previous
//
#include <hip/hip_runtime.h>
#include <hip/hip_bf16.h>

typedef short  short8  __attribute__((ext_vector_type(8)));
typedef float  float4v __attribute__((ext_vector_type(4)));
typedef int    int4v   __attribute__((ext_vector_type(4)));

#define SEQ    4096
#define DHEAD  64
#define NBLK   64
#define NCHUNK 8         // split factor for full rows (qb 0, 63)
#define CHK    8         // key blocks per split chunk
#define WGPB   78        // units per (b,h): 62 regular + 2*8 split
#define ENTRY_FLOATS 4160   // per split-partial: 64 l + 64*64 o
#define KS_ELEMS (2L * 16 * 4096 * 64)   // bf16 K copy elems (= 16 MB)
// ws layout: [0,16MB) Ks bf16 (swizzled LDS image) | [16MB,32MB) VT bf16 | [32MB,..) partials

__device__ __forceinline__ short f2bf(float f) {
    unsigned u = __float_as_uint(f);
    u += 0x7fffu + ((u >> 16) & 1u);   // RNE to bf16
    return (short)(u >> 16);
}

__device__ __forceinline__ unsigned cvt_pk_bf16(float lo, float hi) {
    unsigned r;
    asm("v_cvt_pk_bf16_f32 %0, %1, %2" : "=v"(r) : "v"(lo), "v"(hi));
    return r;
}

__device__ __forceinline__ void gload16(const void* g, void* l) {
    __builtin_amdgcn_global_load_lds(
        (const __attribute__((address_space(1))) unsigned int*)g,
        (__attribute__((address_space(3))) unsigned int*)l, 16, 0, 0);
}

// ---------------- prep: fp32 -> bf16, swizzled 64x128B LDS image, XCD-aligned -----------
// bh = xcd + 8*(slot>>6) matches main's mapping, so ws[bh] lands in the L2 main reads.
__global__ __launch_bounds__(256)
void bigbird_prep(const float* __restrict__ K,
                  const float* __restrict__ V,
                  short* __restrict__ wsS) {
    __shared__ float tile[64 * 65];
    const int gi   = blockIdx.x;
    const int xcd  = gi & 7;
    const int slot = gi >> 3;              // 0..255
    const int bh   = xcd + 8 * (slot >> 6);
    const int kb   = slot & 63;
    const int t  = threadIdx.x;
    char* Ks = (char*)wsS;
    char* VT = (char*)(wsS + KS_ELEMS);
    const long blk_off = (long)(bh * 64 + kb) * 8192;   // bytes per 64x64 bf16 block

    const int row = t >> 2, seg = t & 3;
    const long gsrc = ((long)bh * SEQ + kb * 64 + row) * DHEAD + seg * 16;

    // K: convert, store at swizzled 16B slots
    {
        const float* kp = K + gsrc;
        short8 s0, s1;
#pragma unroll
        for (int i = 0; i < 4; ++i) {
            float4v x = ((const float4v*)kp)[i];
#pragma unroll
            for (int jj = 0; jj < 4; ++jj) {
                short v = f2bf(x[jj]);
                if (i < 2) s0[i * 4 + jj] = v; else s1[(i - 2) * 4 + jj] = v;
            }
        }
        char* kbase = Ks + blk_off + (long)row * 128;
        const int sw = (row & 7) << 4;
        *(short8*)(kbase + ((seg * 32)      ^ sw)) = s0;
        *(short8*)(kbase + ((seg * 32 + 16) ^ sw)) = s1;
    }
    // V: through LDS transpose, then swizzled store of V^T rows (d-major)
    {
        const float* vp = V + gsrc;
#pragma unroll
        for (int i = 0; i < 4; ++i) {
            float4v x = ((const float4v*)vp)[i];
#pragma unroll
            for (int jj = 0; jj < 4; ++jj)
                tile[row * 65 + seg * 16 + i * 4 + jj] = x[jj];
        }
    }
    __syncthreads();
    {
        const int d = t >> 2, kk = t & 3;
        short8 s0, s1;
#pragma unroll
        for (int i = 0; i < 8; ++i) {
            s0[i] = f2bf(tile[(kk * 16 + i) * 65 + d]);
            s1[i] = f2bf(tile[(kk * 16 + 8 + i) * 65 + d]);
        }
        char* vbase = VT + blk_off + (long)d * 128;
        const int sw = (d & 7) << 4;
        *(short8*)(vbase + ((kk * 32)      ^ sw)) = s0;
        *(short8*)(vbase + ((kk * 32 + 16) ^ sw)) = s1;
    }
}

// ---------------- main: R4 verified optimum — distance-2 counted-vmcnt pipeline ---------
// 3 LDS buffer sets (48KB -> 3 blocks/CU, the L2-pressure sweet spot). Per iteration:
// issue stage(it+2), compute buf[it%3], then s_waitcnt vmcnt(4) (tile it+2's 4 loads
// stay in flight) + raw barrier.
__global__ __launch_bounds__(256, 3)
void bigbird_main(const float* __restrict__ Q,
                  const int* __restrict__ rand_attn,
                  float* __restrict__ out,
                  const short* __restrict__ wsS,
                  float* __restrict__ part) {
    __shared__ short kb_s[3][4096];   // 8KB swizzled K block x3
    __shared__ short vt_s[3][4096];   // 8KB swizzled V^T block x3

    const int gi   = blockIdx.x;
    const int xcd  = gi & 7;
    const int slot = gi >> 3;               // 0..311
    const int bh   = xcd + 8 * (slot / WGPB);
    const int j    = slot % WGPB;
    const bool split = (j >= 62);
    int qb, chunk = 0, nk;
    if (!split) { qb = j + 1; nk = (qb == 1 || qb == 62) ? 7 : 8; }
    else        { int s2 = j - 62; qb = (s2 >> 3) ? 63 : 0; chunk = s2 & 7; nk = CHK; }

    const int tid  = threadIdx.x;
    const int wave = tid >> 6;
    const int lane = tid & 63;
    const int l15  = lane & 15;
    const int quad = lane >> 4;

    const long base = (long)bh * SEQ * DHEAD;
    const char* Ksb = (const char*)wsS + (long)bh * (NBLK * 8192);
    const char* VTb = (const char*)(wsS + KS_ELEMS) + (long)bh * (NBLK * 8192);

    int rnd0 = 0, rnd1 = 0, rnd2 = 0;
    if (!split) {
        const int rbase = (bh * 62 + (qb - 1)) * 3;
        rnd0 = rand_attn[rbase + 0];
        rnd1 = rand_attn[rbase + 1];
        rnd2 = rand_attn[rbase + 2];
    }
    auto kb_of = [&](int it) -> int {
        if (split) return chunk * CHK + it;
        const int nband = (qb == 1 || qb == 62) ? 4 : 5;
        if (it >= nband) {
            const int ir = it - nband;
            return ir == 0 ? rnd0 : ir == 1 ? rnd1 : rnd2;
        }
        if (qb == 1)  return it <= 2 ? it : 63;          // 0,1,2,63
        if (qb == 62) return it == 0 ? 0 : 60 + it;      // 0,61,62,63
        return it == 0 ? 0 : it <= 3 ? qb - 2 + it : 63; // 0,qb-1,qb,qb+1,63
    };

    // Q fragments from fp32, pre-scaled by 1/8 (= 1/sqrt(64), exact)
    short8 aq0, aq1;
    {
        const float* qp = Q + base + (long)(qb * 64 + wave * 16 + l15) * DHEAD + quad * 8;
        float4v x0 = *(const float4v*)(qp);
        float4v x1 = *(const float4v*)(qp + 4);
        float4v x2 = *(const float4v*)(qp + 32);
        float4v x3 = *(const float4v*)(qp + 36);
#pragma unroll
        for (int i = 0; i < 4; ++i) {
            aq0[i]     = f2bf(0.125f * x0[i]);
            aq0[4 + i] = f2bf(0.125f * x1[i]);
            aq1[i]     = f2bf(0.125f * x2[i]);
            aq1[4 + i] = f2bf(0.125f * x3[i]);
        }
    }

    // direct global->LDS staging; exactly 4 gload16 (4 vmcnt events) per thread per stage
    auto stage = [&](int kb, int buf) {
        const char* kg = Ksb + (long)kb * 8192;
        const char* vg = VTb + (long)kb * 8192;
        char* kd = (char*)kb_s[buf];
        char* vd = (char*)vt_s[buf];
        const int off = tid * 16;
        gload16(kg + off,        kd + off);
        gload16(kg + 4096 + off, kd + 4096 + off);
        gload16(vg + off,        vd + off);
        gload16(vg + 4096 + off, vd + 4096 + off);
    };

    float4v o[4];
#pragma unroll
    for (int nt = 0; nt < 4; ++nt) o[nt] = (float4v)0.0f;
    float l_acc = 0.0f;   // per-lane partial denominator for q = wave*16+l15

    // drain Q/rand loads so vmcnt counts ONLY staging loads from here on
    asm volatile("s_waitcnt vmcnt(0) lgkmcnt(0)" ::: "memory");

    stage(kb_of(0), 0);                 // nk >= 7 always, so both prologue stages valid
    stage(kb_of(1), 1);
    asm volatile("s_waitcnt vmcnt(4)" ::: "memory");   // buf0 landed; buf1 in flight
    __builtin_amdgcn_s_barrier();

    for (int it = 0; it < nk; ++it) {
        const int cur = it % 3;
        const bool issue = (it + 2 < nk);   // uniform per block
        if (issue) stage(kb_of(it + 2), (it + 2) % 3);

        __builtin_amdgcn_s_setprio(1);
        // ---- S^T = K * Q^T : p[nt] rows k = nt*16+quad*4+r, col q = l15 ----
        float4v p[4];
#pragma unroll
        for (int nt = 0; nt < 4; ++nt) {
            const int rr = nt * 16 + l15;
            const char* kro = (const char*)kb_s[cur] + rr * 128;
            const int sw = (rr & 7) << 4;
            short8 b0 = *(const short8*)(kro + ((quad * 16)      ^ sw));
            short8 b1 = *(const short8*)(kro + ((64 + quad * 16) ^ sw));
            float4v acc = (float4v)0.0f;
            acc = __builtin_amdgcn_mfma_f32_16x16x32_bf16(b0, aq0, acc, 0, 0, 0);
            acc = __builtin_amdgcn_mfma_f32_16x16x32_bf16(b1, aq1, acc, 0, 0, 0);
            p[nt] = acc;
        }

        // ---- fixed-max softmax: P = exp(S); per-lane partial l ----
#pragma unroll
        for (int nt = 0; nt < 4; ++nt) {
#pragma unroll
            for (int r = 0; r < 4; ++r) p[nt][r] = __expf(p[nt][r]);
        }
        l_acc += ((p[0][0] + p[0][1]) + (p[0][2] + p[0][3]))
               + ((p[1][0] + p[1][1]) + (p[1][2] + p[1][3]))
               + ((p[2][0] + p[2][1]) + (p[2][2] + p[2][3]))
               + ((p[3][0] + p[3][1]) + (p[3][2] + p[3][3]));

        // ---- O^T += V^T * P^T ; P^T B-fragment built in-register via permlane swaps ----
#pragma unroll
        for (int f = 0; f < 2; ++f) {
            unsigned x0 = cvt_pk_bf16(p[2 * f][0],     p[2 * f][1]);
            unsigned x1 = cvt_pk_bf16(p[2 * f][2],     p[2 * f][3]);
            unsigned y0 = cvt_pk_bf16(p[2 * f + 1][0], p[2 * f + 1][1]);
            unsigned y1 = cvt_pk_bf16(p[2 * f + 1][2], p[2 * f + 1][3]);
            asm("v_permlane32_swap_b32 %0, %1" : "+v"(x0), "+v"(y0));
            asm("v_permlane32_swap_b32 %0, %1" : "+v"(x1), "+v"(y1));
            asm("v_permlane16_swap_b32 %0, %1" : "+v"(x0), "+v"(y0));
            asm("v_permlane16_swap_b32 %0, %1" : "+v"(x1), "+v"(y1));
            int4v wi; wi[0] = (int)x0; wi[1] = (int)x1; wi[2] = (int)y0; wi[3] = (int)y1;
            union { int4v i; short8 s; } pu; pu.i = wi;
            const short8 pf = pu.s;   // element i = P^T[k = f*32 + quad*8 + i][q = l15]
#pragma unroll
            for (int nt = 0; nt < 4; ++nt) {
                const int rr = nt * 16 + l15;
                const char* vro = (const char*)vt_s[cur] + rr * 128;
                const int sw = (rr & 7) << 4;
                short8 bv = *(const short8*)(vro + ((f * 64 + quad * 16) ^ sw));
                o[nt] = __builtin_amdgcn_mfma_f32_16x16x32_bf16(bv, pf, o[nt], 0, 0, 0);
            }
        }
        __builtin_amdgcn_s_setprio(0);

        // counted drain: require tile it+1's 4 loads done; it+2's 4 may stay in flight
        if (issue) asm volatile("s_waitcnt vmcnt(4)" ::: "memory");
        else       asm volatile("s_waitcnt vmcnt(0)" ::: "memory");
        __builtin_amdgcn_s_barrier();
    }

    // full denominator: sum the 4 quads holding this q's k-partials
    l_acc += __shfl_xor(l_acc, 16, 64);
    l_acc += __shfl_xor(l_acc, 32, 64);

    if (!split) {
        const float inv = 1.0f / l_acc;
        float* op = out + base + (long)(qb * 64 + wave * 16 + l15) * DHEAD;
#pragma unroll
        for (int nt = 0; nt < 4; ++nt) {
            float4v vv;
#pragma unroll
            for (int r = 0; r < 4; ++r) vv[r] = o[nt][r] * inv;
            *(float4v*)(op + nt * 16 + quad * 4) = vv;   // row q, cols nt*16+quad*4..+3
        }
    } else {
        float* wsp = part + (long)((bh * 2 + (qb == 63)) * NCHUNK + chunk) * ENTRY_FLOATS;
        if (quad == 0) wsp[wave * 16 + l15] = l_acc;
        float* orow = wsp + 64 + (long)(wave * 16 + l15) * 64;
#pragma unroll
        for (int nt = 0; nt < 4; ++nt) {
            float4v vv;
#pragma unroll
            for (int r = 0; r < 4; ++r) vv[r] = o[nt][r];
            *(float4v*)(orow + nt * 16 + quad * 4) = vv;
        }
    }
}

// ---------------- combine for split rows (plain sums; fixed-max softmax) ----------------
__global__ __launch_bounds__(256)
void bigbird_combine(const float* __restrict__ part, float* __restrict__ out) {
    const int gid = blockIdx.x * 256 + threadIdx.x;   // 262144 total
    const int dim = gid & 63;
    const int row = (gid >> 6) & 63;
    const int sel = (gid >> 12) & 1;
    const int bh  = gid >> 13;

    float num = 0.0f, den = 0.0f;
#pragma unroll
    for (int c = 0; c < NCHUNK; ++c) {
        const float* e = part + (long)((bh * 2 + sel) * NCHUNK + c) * ENTRY_FLOATS;
        den += e[row];
        num += e[64 + row * 64 + dim];
    }
    const int qb = sel ? 63 : 0;
    out[((long)bh * SEQ + qb * 64 + row) * DHEAD + dim] = num / den;
}

extern "C" void kernel_launch(void* const* d_in, const int* in_sizes, int n_in,
                              void* d_out, int out_size, void* d_ws, size_t ws_size,
                              hipStream_t stream) {
    const float* Q       = (const float*)d_in[0];
    const float* K       = (const float*)d_in[1];
    const float* V       = (const float*)d_in[2];
    const int* rand_attn = (const int*)d_in[3];
    float* out           = (float*)d_out;
    short* wsS           = (short*)d_ws;
    float* part          = (float*)((char*)d_ws + 2L * KS_ELEMS * sizeof(short));

    const int B = 2, H = 16;
    bigbird_prep<<<dim3(B * H * NBLK), dim3(256), 0, stream>>>(K, V, wsS);
    bigbird_main<<<dim3(B * H * WGPB), dim3(256), 0, stream>>>(Q, rand_attn, out, wsS, part);
    bigbird_combine<<<dim3((B * H * 2 * 64 * 64) / 256), dim3(256), 0, stream>>>(part, out);
}